// Round 1
// baseline (353.502 us; speedup 1.0000x reference)
//
#include <hip/hip_runtime.h>
#include <hip/hip_bf16.h>
#include <math.h>

// Problem constants
// B=4, N=2048, C=320, H=5, D=64, INNER=320, BH=20
// scale = 1/8; folded into q along with log2(e) so softmax uses exp2.

typedef short bf16x8 __attribute__((ext_vector_type(8)));
typedef float f32x4 __attribute__((ext_vector_type(4)));

__device__ __forceinline__ ushort f2bf(float f) {
  union { float f; unsigned u; } v; v.f = f;
  unsigned r = (v.u + 0x7fffu + ((v.u >> 16) & 1u)) >> 16;
  return (ushort)r;
}
__device__ __forceinline__ float bf2f(ushort u) {
  union { unsigned u; float f; } v; v.u = ((unsigned)u) << 16;
  return v.f;
}

// ---------------------------------------------------------------------------
// Kernel 1: QKV projection (fp32 tiled GEMM) + head-split + edge/scale folding
//   x (8192,320) @ W (320,320) -> per-head bf16 tensors:
//   z=0: qp[bh][n][d] = q * 0.125*log2e * e_bh[n]
//   z=1: kp[bh][n][d] = k * e_bh[n]
//   z=2: vT[bh][d][n] = v   (transposed for PV B-operand loads)
//   where e_bh = edge[(b+h)%4]  (batch-minor edge tiling vs batch-major heads)
// Block tile 128x64, thread tile 8x4, K staged in 32-chunks.
// ---------------------------------------------------------------------------
__global__ __launch_bounds__(256) void qkv_kernel(
    const float* __restrict__ x, const float* __restrict__ edge,
    const float* __restrict__ Wq, const float* __restrict__ Wk,
    const float* __restrict__ Wv,
    ushort* __restrict__ qp, ushort* __restrict__ kp, ushort* __restrict__ vT)
{
  __shared__ float xsT[32][132];  // [kk][row], 528B row stride (16B aligned)
  __shared__ float wsd[32][68];   // [kk][col], 272B row stride (16B aligned)
  const int mt = blockIdx.x;      // 64 tiles of 128 rows
  const int h  = blockIdx.y;      // head == 64-col tile of the 320-wide output
  const int z  = blockIdx.z;      // 0:q 1:k 2:v
  const float* __restrict__ W = (z == 0) ? Wq : (z == 1 ? Wk : Wv);
  const int tid = threadIdx.x;
  const int ty = tid >> 4, tx = tid & 15;
  const int row0 = mt * 128, c0 = h * 64;

  float acc[8][4];
  for (int i = 0; i < 8; ++i)
    for (int j = 0; j < 4; ++j) acc[i][j] = 0.f;

  for (int k0 = 0; k0 < 320; k0 += 32) {
    // stage x tile 128x32 (transposed into LDS)
    for (int i = 0; i < 4; ++i) {
      int idx = tid + i * 256;
      int r = idx >> 3, c4 = (idx & 7) << 2;
      float4 v = *reinterpret_cast<const float4*>(&x[(size_t)(row0 + r) * 320 + k0 + c4]);
      xsT[c4 + 0][r] = v.x; xsT[c4 + 1][r] = v.y;
      xsT[c4 + 2][r] = v.z; xsT[c4 + 3][r] = v.w;
    }
    // stage W tile 32x64
    for (int i = 0; i < 2; ++i) {
      int idx = tid + i * 256;
      int r = idx >> 4, c4 = (idx & 15) << 2;
      float4 v = *reinterpret_cast<const float4*>(&W[(size_t)(k0 + r) * 320 + c0 + c4]);
      *reinterpret_cast<float4*>(&wsd[r][c4]) = v;
    }
    __syncthreads();
    for (int kk = 0; kk < 32; ++kk) {
      const float4 a0 = *reinterpret_cast<const float4*>(&xsT[kk][ty * 8]);
      const float4 a1 = *reinterpret_cast<const float4*>(&xsT[kk][ty * 8 + 4]);
      const float4 bv = *reinterpret_cast<const float4*>(&wsd[kk][tx * 4]);
      const float a[8] = {a0.x, a0.y, a0.z, a0.w, a1.x, a1.y, a1.z, a1.w};
      const float bb[4] = {bv.x, bv.y, bv.z, bv.w};
      for (int i = 0; i < 8; ++i)
        for (int j = 0; j < 4; ++j)
          acc[i][j] = fmaf(a[i], bb[j], acc[i][j]);
    }
    __syncthreads();
  }

  // epilogue: fold edge / scale, write bf16 in per-head layouts
  const float QSCALE = 0.18033688011112042f;  // 0.125 * log2(e)
  for (int i = 0; i < 8; ++i) {
    int m = row0 + ty * 8 + i;
    int bb = m >> 11, n = m & 2047;
    int ebi = (bb + h) & 3;
    float e = edge[ebi * 2048 + n];
    int bh = bb * 5 + h;
    for (int j = 0; j < 4; ++j) {
      int d = tx * 4 + j;
      float vv = acc[i][j];
      if (z == 0)
        qp[((size_t)(bh * 2048 + n)) * 64 + d] = f2bf(vv * QSCALE * e);
      else if (z == 1)
        kp[((size_t)(bh * 2048 + n)) * 64 + d] = f2bf(vv * e);
      else
        vT[((size_t)bh * 64 + d) * 2048 + n] = f2bf(vv);
    }
  }
}

// ---------------------------------------------------------------------------
// Kernel 2: flash-style attention, bf16 MFMA 16x16x32.
// Grid (32 q-tiles, 20 bh). Block = 4 waves; wave handles 16 q-rows.
// Logits are bounded (|s| <~ 10) -> no online max needed; p = exp2(s).
// Row sums accumulated per-lane, one 16-lane shuffle reduce at the end.
// P goes C/D-layout -> LDS -> A-operand layout (verified m120 pattern).
// ---------------------------------------------------------------------------
__global__ __launch_bounds__(256) void attn_kernel(
    const ushort* __restrict__ qp, const ushort* __restrict__ kp,
    const ushort* __restrict__ vT, ushort* __restrict__ ao)
{
  __shared__ ushort pbuf[4][16][64];  // per-wave P tile (16 q x 64 j), 8 KB
  const int qt = blockIdx.x;          // 64-row q tile
  const int bh = blockIdx.y;          // b*5 + h
  const int b = bh / 5, h = bh % 5;
  const int wave = threadIdx.x >> 6, lane = threadIdx.x & 63;
  const int m16 = lane & 15, quad = lane >> 4;

  // Q A-fragments: lane holds Q[m=lane&15][k=quad*8+j], two 32-wide k chunks
  const ushort* qrow_p = qp + ((size_t)bh * 2048 + qt * 64 + wave * 16 + m16) * 64;
  const bf16x8 qf0 = *reinterpret_cast<const bf16x8*>(qrow_p + quad * 8);
  const bf16x8 qf1 = *reinterpret_cast<const bf16x8*>(qrow_p + 32 + quad * 8);

  const ushort* kb = kp + (size_t)bh * 2048 * 64;
  const ushort* vb = vT + (size_t)bh * 64 * 2048;

  f32x4 oacc[4];
  float rs[4];
  for (int i = 0; i < 4; ++i) {
    oacc[i] = (f32x4){0.f, 0.f, 0.f, 0.f};
    rs[i] = 0.f;
  }

  for (int jt = 0; jt < 32; ++jt) {
    const int j0 = jt * 64;
    // S = Q K^T  (4 j-subtiles of 16)
    f32x4 s[4];
    for (int nt = 0; nt < 4; ++nt) {
      const ushort* kr = kb + (size_t)(j0 + nt * 16 + m16) * 64 + quad * 8;
      const bf16x8 kf0 = *reinterpret_cast<const bf16x8*>(kr);
      const bf16x8 kf1 = *reinterpret_cast<const bf16x8*>(kr + 32);
      f32x4 z = (f32x4){0.f, 0.f, 0.f, 0.f};
      s[nt] = __builtin_amdgcn_mfma_f32_16x16x32_bf16(qf0, kf0, z, 0, 0, 0);
      s[nt] = __builtin_amdgcn_mfma_f32_16x16x32_bf16(qf1, kf1, s[nt], 0, 0, 0);
    }
    // P = exp2(S); accumulate per-lane row partial sums; spill P to LDS (bf16)
    for (int nt = 0; nt < 4; ++nt) {
      for (int r = 0; r < 4; ++r) {
        float p = exp2f(s[nt][r]);
        rs[r] += p;
        pbuf[wave][quad * 4 + r][nt * 16 + m16] = f2bf(p);
      }
    }
    // read P back in A-operand layout
    const bf16x8 pf0 = *reinterpret_cast<const bf16x8*>(&pbuf[wave][m16][quad * 8]);
    const bf16x8 pf1 = *reinterpret_cast<const bf16x8*>(&pbuf[wave][m16][32 + quad * 8]);
    // O += P V : vT rows give B-operand contiguously
    for (int nt = 0; nt < 4; ++nt) {
      const ushort* vr = vb + (size_t)(nt * 16 + m16) * 2048 + j0 + quad * 8;
      const bf16x8 vf0 = *reinterpret_cast<const bf16x8*>(vr);
      const bf16x8 vf1 = *reinterpret_cast<const bf16x8*>(vr + 32);
      oacc[nt] = __builtin_amdgcn_mfma_f32_16x16x32_bf16(pf0, vf0, oacc[nt], 0, 0, 0);
      oacc[nt] = __builtin_amdgcn_mfma_f32_16x16x32_bf16(pf1, vf1, oacc[nt], 0, 0, 0);
    }
  }

  // reduce row sums across the 16 lanes of each quad
  for (int off = 1; off < 16; off <<= 1)
    for (int r = 0; r < 4; ++r)
      rs[r] += __shfl_xor(rs[r], off, 64);

  // normalize and write merged-head layout ao[b][n][h*64+d] (bf16)
  const int nbase = qt * 64 + wave * 16 + quad * 4;
  for (int r = 0; r < 4; ++r) {
    float inv = 1.0f / rs[r];
    int n = nbase + r;
    for (int nt = 0; nt < 4; ++nt) {
      int d = nt * 16 + m16;
      ao[((size_t)(b * 2048 + n)) * 320 + h * 64 + d] = f2bf(oacc[nt][r] * inv);
    }
  }
}

// ---------------------------------------------------------------------------
// Kernel 3: output projection (fp32 tiled GEMM): ao(8192,320)bf16 @ Wo + bo
// ---------------------------------------------------------------------------
__global__ __launch_bounds__(256) void oproj_kernel(
    const ushort* __restrict__ ao, const float* __restrict__ Wo,
    const float* __restrict__ bo, float* __restrict__ out)
{
  __shared__ float xsT[32][132];
  __shared__ float wsd[32][68];
  const int mt = blockIdx.x, ct = blockIdx.y;
  const int tid = threadIdx.x;
  const int ty = tid >> 4, tx = tid & 15;
  const int row0 = mt * 128, c0 = ct * 64;

  float acc[8][4];
  for (int i = 0; i < 8; ++i)
    for (int j = 0; j < 4; ++j) acc[i][j] = 0.f;

  for (int k0 = 0; k0 < 320; k0 += 32) {
    for (int i = 0; i < 4; ++i) {
      int idx = tid + i * 256;
      int r = idx >> 3, c4 = (idx & 7) << 2;
      ushort4 v = *reinterpret_cast<const ushort4*>(&ao[(size_t)(row0 + r) * 320 + k0 + c4]);
      xsT[c4 + 0][r] = bf2f(v.x); xsT[c4 + 1][r] = bf2f(v.y);
      xsT[c4 + 2][r] = bf2f(v.z); xsT[c4 + 3][r] = bf2f(v.w);
    }
    for (int i = 0; i < 2; ++i) {
      int idx = tid + i * 256;
      int r = idx >> 4, c4 = (idx & 15) << 2;
      float4 v = *reinterpret_cast<const float4*>(&Wo[(size_t)(k0 + r) * 320 + c0 + c4]);
      *reinterpret_cast<float4*>(&wsd[r][c4]) = v;
    }
    __syncthreads();
    for (int kk = 0; kk < 32; ++kk) {
      const float4 a0 = *reinterpret_cast<const float4*>(&xsT[kk][ty * 8]);
      const float4 a1 = *reinterpret_cast<const float4*>(&xsT[kk][ty * 8 + 4]);
      const float4 bv = *reinterpret_cast<const float4*>(&wsd[kk][tx * 4]);
      const float a[8] = {a0.x, a0.y, a0.z, a0.w, a1.x, a1.y, a1.z, a1.w};
      const float bb[4] = {bv.x, bv.y, bv.z, bv.w};
      for (int i = 0; i < 8; ++i)
        for (int j = 0; j < 4; ++j)
          acc[i][j] = fmaf(a[i], bb[j], acc[i][j]);
    }
    __syncthreads();
  }

  const float4 bv = *reinterpret_cast<const float4*>(&bo[c0 + tx * 4]);
  const float bb[4] = {bv.x, bv.y, bv.z, bv.w};
  for (int i = 0; i < 8; ++i) {
    size_t m = row0 + ty * 8 + i;
    float4 o;
    o.x = acc[i][0] + bb[0]; o.y = acc[i][1] + bb[1];
    o.z = acc[i][2] + bb[2]; o.w = acc[i][3] + bb[3];
    *reinterpret_cast<float4*>(&out[m * 320 + c0 + tx * 4]) = o;
  }
}

// ---------------------------------------------------------------------------
extern "C" void kernel_launch(void* const* d_in, const int* in_sizes, int n_in,
                              void* d_out, int out_size, void* d_ws, size_t ws_size,
                              hipStream_t stream) {
  const float* x    = (const float*)d_in[0];
  const float* edge = (const float*)d_in[1];
  const float* Wq   = (const float*)d_in[2];
  const float* Wk   = (const float*)d_in[3];
  const float* Wv   = (const float*)d_in[4];
  const float* Wo   = (const float*)d_in[5];
  const float* bo   = (const float*)d_in[6];
  float* out = (float*)d_out;

  // workspace layout (bf16): qp, kp, vT: (20,2048,64); ao: (4,2048,320) => 21 MB
  ushort* qp = (ushort*)d_ws;
  ushort* kp = qp + (size_t)20 * 2048 * 64;
  ushort* vT = kp + (size_t)20 * 2048 * 64;
  ushort* ao = vT + (size_t)20 * 2048 * 64;

  qkv_kernel<<<dim3(64, 5, 3), 256, 0, stream>>>(x, edge, Wq, Wk, Wv, qp, kp, vT);
  attn_kernel<<<dim3(32, 20), 256, 0, stream>>>(qp, kp, vT, ao);
  oproj_kernel<<<dim3(64, 5), 256, 0, stream>>>(ao, Wo, bo, out);
}

// Round 2
// 346.608 us; speedup vs baseline: 1.0199x; 1.0199x over previous
//
#include <hip/hip_runtime.h>
#include <hip/hip_bf16.h>
#include <math.h>

// B=4, N=2048, C=320, H=5, D=64, INNER=320, BH=20
// logit = (q*0.125*log2e*e_i) . (k*e_j); softmax via exp2, no max needed
// (|logit| <~ 8, bounded).

typedef short bf16x8 __attribute__((ext_vector_type(8)));
typedef short bf16x4 __attribute__((ext_vector_type(4)));
typedef float f32x4 __attribute__((ext_vector_type(4)));

__device__ __forceinline__ ushort f2bf(float f) {
  union { float f; unsigned u; } v; v.f = f;
  unsigned r = (v.u + 0x7fffu + ((v.u >> 16) & 1u)) >> 16;
  return (ushort)r;
}
__device__ __forceinline__ float bf2f(ushort u) {
  union { unsigned u; float f; } v; v.u = ((unsigned)u) << 16;
  return v.f;
}
__device__ __forceinline__ float fexp2(float x) {
#if __has_builtin(__builtin_amdgcn_exp2f)
  return __builtin_amdgcn_exp2f(x);
#else
  return exp2f(x);
#endif
}
__device__ __forceinline__ f32x4 mfma16(bf16x4 a, bf16x4 b, f32x4 c) {
#if __has_builtin(__builtin_amdgcn_mfma_f32_16x16x16bf16_1k)
  return __builtin_amdgcn_mfma_f32_16x16x16bf16_1k(a, b, c, 0, 0, 0);
#else
  asm volatile("s_nop 7\n\tv_mfma_f32_16x16x16_bf16 %0, %1, %2, %0\n\ts_nop 7"
               : "+v"(c) : "v"(a), "v"(b));
  return c;
#endif
}

// ---------------------------------------------------------------------------
// Kernel 1: QKV projection (fp32 tiled GEMM) + head-split + edge/scale folding
//   z=0: qp[bh][n][d] = q * 0.125*log2e * e_bh[n]
//   z=1: kp[bh][n][d] = k * e_bh[n]
//   z=2: vS[bh][d][swz(n)] = v   (transposed + j-bit-swizzled for PV A-frags)
//   swz swaps bits [3:2] and [5:4] of n so that an attention lane's 16 needed
//   j-values (4 k-subtiles x k=quad*4+jj) are 16 contiguous bf16.
//   e_bh = edge[(b+h)%4]  (batch-minor edge tiling vs batch-major heads)
// ---------------------------------------------------------------------------
__global__ __launch_bounds__(256) void qkv_kernel(
    const float* __restrict__ x, const float* __restrict__ edge,
    const float* __restrict__ Wq, const float* __restrict__ Wk,
    const float* __restrict__ Wv,
    ushort* __restrict__ qp, ushort* __restrict__ kp, ushort* __restrict__ vS)
{
  __shared__ float xsT[32][132];
  __shared__ float wsd[32][68];
  const int mt = blockIdx.x;
  const int h  = blockIdx.y;
  const int z  = blockIdx.z;
  const float* __restrict__ W = (z == 0) ? Wq : (z == 1 ? Wk : Wv);
  const int tid = threadIdx.x;
  const int ty = tid >> 4, tx = tid & 15;
  const int row0 = mt * 128, c0 = h * 64;

  float acc[8][4];
  for (int i = 0; i < 8; ++i)
    for (int j = 0; j < 4; ++j) acc[i][j] = 0.f;

  for (int k0 = 0; k0 < 320; k0 += 32) {
    for (int i = 0; i < 4; ++i) {
      int idx = tid + i * 256;
      int r = idx >> 3, c4 = (idx & 7) << 2;
      float4 v = *reinterpret_cast<const float4*>(&x[(size_t)(row0 + r) * 320 + k0 + c4]);
      xsT[c4 + 0][r] = v.x; xsT[c4 + 1][r] = v.y;
      xsT[c4 + 2][r] = v.z; xsT[c4 + 3][r] = v.w;
    }
    for (int i = 0; i < 2; ++i) {
      int idx = tid + i * 256;
      int r = idx >> 4, c4 = (idx & 15) << 2;
      float4 v = *reinterpret_cast<const float4*>(&W[(size_t)(k0 + r) * 320 + c0 + c4]);
      *reinterpret_cast<float4*>(&wsd[r][c4]) = v;
    }
    __syncthreads();
    for (int kk = 0; kk < 32; ++kk) {
      const float4 a0 = *reinterpret_cast<const float4*>(&xsT[kk][ty * 8]);
      const float4 a1 = *reinterpret_cast<const float4*>(&xsT[kk][ty * 8 + 4]);
      const float4 bv = *reinterpret_cast<const float4*>(&wsd[kk][tx * 4]);
      const float a[8] = {a0.x, a0.y, a0.z, a0.w, a1.x, a1.y, a1.z, a1.w};
      const float bb[4] = {bv.x, bv.y, bv.z, bv.w};
      for (int i = 0; i < 8; ++i)
        for (int j = 0; j < 4; ++j)
          acc[i][j] = fmaf(a[i], bb[j], acc[i][j]);
    }
    __syncthreads();
  }

  const float QSCALE = 0.18033688011112042f;  // 0.125 * log2(e)
  for (int i = 0; i < 8; ++i) {
    int m = row0 + ty * 8 + i;
    int bb = m >> 11, n = m & 2047;
    int ebi = (bb + h) & 3;
    float e = edge[ebi * 2048 + n];
    int bh = bb * 5 + h;
    for (int j = 0; j < 4; ++j) {
      int d = tx * 4 + j;
      float vv = acc[i][j];
      if (z == 0)
        qp[((size_t)(bh * 2048 + n)) * 64 + d] = f2bf(vv * QSCALE * e);
      else if (z == 1)
        kp[((size_t)(bh * 2048 + n)) * 64 + d] = f2bf(vv * e);
      else {
        int p = (n & ~63) | ((n & 12) << 2) | ((n >> 2) & 12) | (n & 3);
        vS[((size_t)bh * 64 + d) * 2048 + p] = f2bf(vv);
      }
    }
  }
}

// ---------------------------------------------------------------------------
// Kernel 2: attention, transposed formulation, zero LDS.
//   S^T = K Q^T via mfma_16x16x32(kf, qf): lane holds S^T[j=quad*4+r][q=m16]
//   P^T = exp2(S^T), truncated to bf16 in-register (2 v_perm per 4 vals);
//   rowsum from the SAME truncated values -> exact consistency.
//   O^T[dtile] += mfma_16x16x16(V^T-frag, P^T-frag): B-operand k=quad*4+jj
//   matches C-layout row=quad*4+r directly. rowsum reduce = 2 shuffles.
// ---------------------------------------------------------------------------
__global__ __launch_bounds__(256) void attn_kernel(
    const ushort* __restrict__ qp, const ushort* __restrict__ kp,
    const ushort* __restrict__ vS, ushort* __restrict__ ao)
{
  const int qt = blockIdx.x, bh = blockIdx.y;
  const int b = bh / 5, h = bh % 5;
  const int wave = threadIdx.x >> 6, lane = threadIdx.x & 63;
  const int m16 = lane & 15, quad = lane >> 4;
  const int q0 = qt * 64 + wave * 16;

  const ushort* qrow = qp + ((size_t)bh * 2048 + q0 + m16) * 64;
  const bf16x8 qf0 = *reinterpret_cast<const bf16x8*>(qrow + quad * 8);
  const bf16x8 qf1 = *reinterpret_cast<const bf16x8*>(qrow + 32 + quad * 8);

  const ushort* kb = kp + (size_t)bh * 2048 * 64;
  const ushort* vb = vS + (size_t)bh * 64 * 2048;

  f32x4 oacc[4];
  for (int i = 0; i < 4; ++i) oacc[i] = (f32x4){0.f, 0.f, 0.f, 0.f};
  float rs = 0.f;

  for (int jt = 0; jt < 32; ++jt) {
    const int j0 = jt * 64;
    // S^T tiles: 4 j-subtiles of 16
    f32x4 st[4];
#pragma unroll
    for (int nt = 0; nt < 4; ++nt) {
      const ushort* kr = kb + (size_t)(j0 + nt * 16 + m16) * 64 + quad * 8;
      bf16x8 kf0 = *reinterpret_cast<const bf16x8*>(kr);
      bf16x8 kf1 = *reinterpret_cast<const bf16x8*>(kr + 32);
      f32x4 z = (f32x4){0.f, 0.f, 0.f, 0.f};
      st[nt] = __builtin_amdgcn_mfma_f32_16x16x32_bf16(kf0, qf0, z, 0, 0, 0);
      st[nt] = __builtin_amdgcn_mfma_f32_16x16x32_bf16(kf1, qf1, st[nt], 0, 0, 0);
    }
    // V^T A-frags from swizzled layout: 2 x b128 per d-tile
    bf16x4 vfr[4][4];  // [dtile][ksubtile]
#pragma unroll
    for (int dt = 0; dt < 4; ++dt) {
      const ushort* vr = vb + (size_t)(dt * 16 + m16) * 2048 + j0 + quad * 16;
      union { bf16x8 v8; bf16x4 v4[2]; } lo, hi;
      lo.v8 = *reinterpret_cast<const bf16x8*>(vr);
      hi.v8 = *reinterpret_cast<const bf16x8*>(vr + 8);
      vfr[dt][0] = lo.v4[0]; vfr[dt][1] = lo.v4[1];
      vfr[dt][2] = hi.v4[0]; vfr[dt][3] = hi.v4[1];
    }
    // exp2, truncate-pack, accumulate PV
#pragma unroll
    for (int nt = 0; nt < 4; ++nt) {
      float p0 = fexp2(st[nt][0]), p1 = fexp2(st[nt][1]);
      float p2 = fexp2(st[nt][2]), p3 = fexp2(st[nt][3]);
      unsigned b0 = __float_as_uint(p0), b1 = __float_as_uint(p1);
      unsigned b2 = __float_as_uint(p2), b3 = __float_as_uint(p3);
      // rowsum over the truncated values (consistent with P fed to MFMA)
      rs += __uint_as_float(b0 & 0xffff0000u) + __uint_as_float(b1 & 0xffff0000u)
          + __uint_as_float(b2 & 0xffff0000u) + __uint_as_float(b3 & 0xffff0000u);
      union { unsigned u[2]; bf16x4 s; } pk;
      pk.u[0] = __builtin_amdgcn_perm(b1, b0, 0x07060302u);
      pk.u[1] = __builtin_amdgcn_perm(b3, b2, 0x07060302u);
#pragma unroll
      for (int dt = 0; dt < 4; ++dt)
        oacc[dt] = mfma16(vfr[dt][nt], pk.s, oacc[dt]);
    }
  }

  // rowsum: lane's rs covers its 16 j; sum across the 4 quads (same m16)
  rs += __shfl_xor(rs, 16, 64);
  rs += __shfl_xor(rs, 32, 64);
  const float inv = 1.0f / rs;

  // O^T C-layout: lane holds d = dt*16 + quad*4 + r, q-row = m16 (all same n)
  const int n = q0 + m16;
  ushort* orow = ao + ((size_t)(b * 2048 + n)) * 320 + h * 64;
#pragma unroll
  for (int dt = 0; dt < 4; ++dt) {
    int d0 = dt * 16 + quad * 4;
    unsigned r0 = f2bf(oacc[dt][0] * inv), r1 = f2bf(oacc[dt][1] * inv);
    unsigned r2 = f2bf(oacc[dt][2] * inv), r3 = f2bf(oacc[dt][3] * inv);
    uint2 w;
    w.x = r0 | (r1 << 16);
    w.y = r2 | (r3 << 16);
    *reinterpret_cast<uint2*>(orow + d0) = w;
  }
}

// ---------------------------------------------------------------------------
// Kernel 3: output projection (fp32 tiled GEMM): ao(8192,320)bf16 @ Wo + bo
// ---------------------------------------------------------------------------
__global__ __launch_bounds__(256) void oproj_kernel(
    const ushort* __restrict__ ao, const float* __restrict__ Wo,
    const float* __restrict__ bo, float* __restrict__ out)
{
  __shared__ float xsT[32][132];
  __shared__ float wsd[32][68];
  const int mt = blockIdx.x, ct = blockIdx.y;
  const int tid = threadIdx.x;
  const int ty = tid >> 4, tx = tid & 15;
  const int row0 = mt * 128, c0 = ct * 64;

  float acc[8][4];
  for (int i = 0; i < 8; ++i)
    for (int j = 0; j < 4; ++j) acc[i][j] = 0.f;

  for (int k0 = 0; k0 < 320; k0 += 32) {
    for (int i = 0; i < 4; ++i) {
      int idx = tid + i * 256;
      int r = idx >> 3, c4 = (idx & 7) << 2;
      ushort4 v = *reinterpret_cast<const ushort4*>(&ao[(size_t)(row0 + r) * 320 + k0 + c4]);
      xsT[c4 + 0][r] = bf2f(v.x); xsT[c4 + 1][r] = bf2f(v.y);
      xsT[c4 + 2][r] = bf2f(v.z); xsT[c4 + 3][r] = bf2f(v.w);
    }
    for (int i = 0; i < 2; ++i) {
      int idx = tid + i * 256;
      int r = idx >> 4, c4 = (idx & 15) << 2;
      float4 v = *reinterpret_cast<const float4*>(&Wo[(size_t)(k0 + r) * 320 + c0 + c4]);
      *reinterpret_cast<float4*>(&wsd[r][c4]) = v;
    }
    __syncthreads();
    for (int kk = 0; kk < 32; ++kk) {
      const float4 a0 = *reinterpret_cast<const float4*>(&xsT[kk][ty * 8]);
      const float4 a1 = *reinterpret_cast<const float4*>(&xsT[kk][ty * 8 + 4]);
      const float4 bv = *reinterpret_cast<const float4*>(&wsd[kk][tx * 4]);
      const float a[8] = {a0.x, a0.y, a0.z, a0.w, a1.x, a1.y, a1.z, a1.w};
      const float bb[4] = {bv.x, bv.y, bv.z, bv.w};
      for (int i = 0; i < 8; ++i)
        for (int j = 0; j < 4; ++j)
          acc[i][j] = fmaf(a[i], bb[j], acc[i][j]);
    }
    __syncthreads();
  }

  const float4 bv = *reinterpret_cast<const float4*>(&bo[c0 + tx * 4]);
  const float bb[4] = {bv.x, bv.y, bv.z, bv.w};
  for (int i = 0; i < 8; ++i) {
    size_t m = row0 + ty * 8 + i;
    float4 o;
    o.x = acc[i][0] + bb[0]; o.y = acc[i][1] + bb[1];
    o.z = acc[i][2] + bb[2]; o.w = acc[i][3] + bb[3];
    *reinterpret_cast<float4*>(&out[m * 320 + c0 + tx * 4]) = o;
  }
}

// ---------------------------------------------------------------------------
extern "C" void kernel_launch(void* const* d_in, const int* in_sizes, int n_in,
                              void* d_out, int out_size, void* d_ws, size_t ws_size,
                              hipStream_t stream) {
  const float* x    = (const float*)d_in[0];
  const float* edge = (const float*)d_in[1];
  const float* Wq   = (const float*)d_in[2];
  const float* Wk   = (const float*)d_in[3];
  const float* Wv   = (const float*)d_in[4];
  const float* Wo   = (const float*)d_in[5];
  const float* bo   = (const float*)d_in[6];
  float* out = (float*)d_out;

  // workspace (bf16): qp, kp, vS: (20,2048,64); ao: (4,2048,320) => 21 MB
  ushort* qp = (ushort*)d_ws;
  ushort* kp = qp + (size_t)20 * 2048 * 64;
  ushort* vS = kp + (size_t)20 * 2048 * 64;
  ushort* ao = vS + (size_t)20 * 2048 * 64;

  qkv_kernel<<<dim3(64, 5, 3), 256, 0, stream>>>(x, edge, Wq, Wk, Wv, qp, kp, vS);
  attn_kernel<<<dim3(32, 20), 256, 0, stream>>>(qp, kp, vS, ao);
  oproj_kernel<<<dim3(64, 5), 256, 0, stream>>>(ao, Wo, bo, out);
}

// Round 3
// 230.739 us; speedup vs baseline: 1.5320x; 1.5022x over previous
//
#include <hip/hip_runtime.h>
#include <hip/hip_bf16.h>
#include <math.h>

// B=4, N=2048, C=320, H=5, D=64, INNER=320, BH=20
// logit = (q*0.125*log2e*e_i) . (k*e_j); softmax via exp2 (|logit| bounded, no max).
// e_bh = edge[(b+h)%4]  (batch-minor edge tiling vs batch-major heads)

typedef short bf16x8 __attribute__((ext_vector_type(8)));
typedef short bf16x4 __attribute__((ext_vector_type(4)));
typedef float f32x4 __attribute__((ext_vector_type(4)));

static __device__ __forceinline__ ushort f2bf(float f) {
  union { float f; unsigned u; } v; v.f = f;
  unsigned r = (v.u + 0x7fffu + ((v.u >> 16) & 1u)) >> 16;
  return (ushort)r;
}
static __device__ __forceinline__ float fexp2(float x) {
#if __has_builtin(__builtin_amdgcn_exp2f)
  return __builtin_amdgcn_exp2f(x);
#else
  return exp2f(x);
#endif
}
static __device__ __forceinline__ f32x4 mfma32(bf16x8 a, bf16x8 b, f32x4 c) {
  return __builtin_amdgcn_mfma_f32_16x16x32_bf16(a, b, c, 0, 0, 0);
}
static __device__ __forceinline__ f32x4 mfma16(bf16x4 a, bf16x4 b, f32x4 c) {
#if __has_builtin(__builtin_amdgcn_mfma_f32_16x16x16bf16_1k)
  return __builtin_amdgcn_mfma_f32_16x16x16bf16_1k(a, b, c, 0, 0, 0);
#else
  asm volatile("s_nop 7\n\tv_mfma_f32_16x16x16_bf16 %0, %1, %2, %0\n\ts_nop 7"
               : "+v"(c) : "v"(a), "v"(b));
  return c;
#endif
}

// ---------------------------------------------------------------------------
// Prep 1: x fp32 -> bf16 (8192x320 = 655360 float4s, grid 2560 x 256)
// ---------------------------------------------------------------------------
__global__ __launch_bounds__(256) void xcvt_kernel(
    const float* __restrict__ x, ushort* __restrict__ xb)
{
  int idx = blockIdx.x * 256 + threadIdx.x;
  float4 v = reinterpret_cast<const float4*>(x)[idx];
  ushort4 o = { f2bf(v.x), f2bf(v.y), f2bf(v.z), f2bf(v.w) };
  reinterpret_cast<ushort4*>(xb)[idx] = o;
}

// ---------------------------------------------------------------------------
// Prep 2: transpose + convert W (320x320 fp32, k-major) -> WT (n-major bf16)
// wt layout: [z][320 n][320 k], z: 0=Wq 1=Wk 2=Wv 3=Wo
// ---------------------------------------------------------------------------
__global__ __launch_bounds__(256) void wtrans_kernel(
    const float* __restrict__ Wq, const float* __restrict__ Wk,
    const float* __restrict__ Wv, const float* __restrict__ Wo,
    ushort* __restrict__ wt)
{
  __shared__ float t[32][33];
  const float* W = blockIdx.z == 0 ? Wq : blockIdx.z == 1 ? Wk
                 : blockIdx.z == 2 ? Wv : Wo;
  ushort* dst = wt + (size_t)blockIdx.z * 102400;
  const int tx = threadIdx.x, ty = threadIdx.y;  // 32, 8
  const int r0 = blockIdx.x * 32, c0 = blockIdx.y * 32;
#pragma unroll
  for (int i = 0; i < 4; ++i)
    t[ty + i * 8][tx] = W[(size_t)(r0 + ty + i * 8) * 320 + c0 + tx];
  __syncthreads();
#pragma unroll
  for (int i = 0; i < 4; ++i)
    dst[(size_t)(c0 + ty + i * 8) * 320 + r0 + tx] = f2bf(t[tx][ty + i * 8]);
}

// ---------------------------------------------------------------------------
// Kernel 1: QKV projection, bf16 MFMA, LDS-free (weights are L2-resident).
// grid (128 mt, 5 h, 3 z); block 4 waves; wave computes 16m x 64n, K=320.
//   z=0: qp[bh][n][d] = q * 0.125*log2e * e_bh[n]
//   z=1: kp[bh][n][d] = k * e_bh[n]
//   z=2: vS[bh][d][swz(n)] = v   (swz swaps bit-pairs [3:2]<->[5:4])
// ---------------------------------------------------------------------------
__global__ __launch_bounds__(256, 6) void qkv_gemm(
    const ushort* __restrict__ xb, const float* __restrict__ edge,
    const ushort* __restrict__ wt,
    ushort* __restrict__ qp, ushort* __restrict__ kp, ushort* __restrict__ vS)
{
  const int mt = blockIdx.x, h = blockIdx.y, z = blockIdx.z;
  const int wave = threadIdx.x >> 6, lane = threadIdx.x & 63;
  const int m16 = lane & 15, quad = lane >> 4;
  const int m0 = mt * 64 + wave * 16;
  const ushort* WTz = wt + (size_t)z * 102400 + (size_t)h * 64 * 320 + quad * 8;
  const ushort* arow = xb + (size_t)(m0 + m16) * 320 + quad * 8;

  f32x4 acc[4];
#pragma unroll
  for (int ns = 0; ns < 4; ++ns) acc[ns] = (f32x4){0.f, 0.f, 0.f, 0.f};

#pragma unroll
  for (int kc = 0; kc < 10; ++kc) {
    bf16x8 af = *reinterpret_cast<const bf16x8*>(arow + kc * 32);
#pragma unroll
    for (int ns = 0; ns < 4; ++ns) {
      bf16x8 bf = *reinterpret_cast<const bf16x8*>(
          WTz + (size_t)(ns * 16 + m16) * 320 + kc * 32);
      acc[ns] = mfma32(af, bf, acc[ns]);
    }
  }

  // C/D: lane holds m = m0 + quad*4 + r (seq), col d = ns*16 + m16
  const float QSCALE = 0.18033688011112042f;  // 0.125 * log2(e)
  const int mrow = m0 + quad * 4;
  const int b = mrow >> 11;       // 64-row blocks never straddle 2048
  const int n = mrow & 2047;
  const int bh = b * 5 + h;
  if (z == 2) {
    const int swzb = (n & ~63) | (quad * 16) | (wave * 4);  // swz(n), r in low 2
#pragma unroll
    for (int ns = 0; ns < 4; ++ns) {
      int d = ns * 16 + m16;
      ushort4 o = { f2bf(acc[ns][0]), f2bf(acc[ns][1]),
                    f2bf(acc[ns][2]), f2bf(acc[ns][3]) };
      *reinterpret_cast<ushort4*>(vS + ((size_t)bh * 64 + d) * 2048 + swzb) = o;
    }
  } else {
    const float* eb = edge + (size_t)((b + h) & 3) * 2048;
    float e[4];
#pragma unroll
    for (int r = 0; r < 4; ++r)
      e[r] = eb[n + r] * (z == 0 ? QSCALE : 1.0f);
    ushort* dst = (z == 0 ? qp : kp) + ((size_t)bh * 2048 + n) * 64;
#pragma unroll
    for (int ns = 0; ns < 4; ++ns) {
      int d = ns * 16 + m16;
#pragma unroll
      for (int r = 0; r < 4; ++r)
        dst[(size_t)r * 64 + d] = f2bf(acc[ns][r] * e[r]);
    }
  }
}

// ---------------------------------------------------------------------------
// Kernel 2: attention, transposed zero-LDS-mainloop formulation + in-block
// j-split for TLP. grid (64 qt, 20 bh) = 1280 blocks; block = 4 waves, all
// on the same 32 q-rows; wave w handles j-tiles jt = w, w+4, ..., w+28.
// Partial O / rowsum combined across waves via LDS at the end.
//   S^T = K Q^T (mfma 16x16x32): lane holds S^T[j=quad*4+r][q=m16]
//   P^T = exp2(S^T) truncated to bf16 in-register -> PV B-operand directly
//   rowsum via mfma16(ones, P^T) -- exactly consistent with P fed to PV
//   O^T[dt] += mfma16(V-frag, P^T)
// ---------------------------------------------------------------------------
__global__ __launch_bounds__(256, 4) void attn_kernel(
    const ushort* __restrict__ qp, const ushort* __restrict__ kp,
    const ushort* __restrict__ vS, ushort* __restrict__ ao)
{
  __shared__ f32x4 lo[3][8][64];   // 24 KB, lane-contiguous (conflict-free)
  __shared__ float lrs[4][2][16];
  const int qt = blockIdx.x, bh = blockIdx.y;
  const int b = bh / 5, h = bh % 5;
  const int wave = threadIdx.x >> 6, lane = threadIdx.x & 63;
  const int m16 = lane & 15, quad = lane >> 4;
  const int q0 = qt * 32;

  bf16x8 qf[2][2];
#pragma unroll
  for (int qs = 0; qs < 2; ++qs) {
    const ushort* qrow = qp + ((size_t)bh * 2048 + q0 + qs * 16 + m16) * 64;
    qf[qs][0] = *reinterpret_cast<const bf16x8*>(qrow + quad * 8);
    qf[qs][1] = *reinterpret_cast<const bf16x8*>(qrow + 32 + quad * 8);
  }
  const ushort* kb = kp + (size_t)bh * 2048 * 64;
  const ushort* vb = vS + (size_t)bh * 64 * 2048;

  f32x4 oacc[2][4], rsacc[2];
#pragma unroll
  for (int qs = 0; qs < 2; ++qs) {
    rsacc[qs] = (f32x4){0.f, 0.f, 0.f, 0.f};
    for (int dt = 0; dt < 4; ++dt) oacc[qs][dt] = (f32x4){0.f, 0.f, 0.f, 0.f};
  }
  const bf16x4 ones = {(short)16256, (short)16256, (short)16256, (short)16256};

  for (int i = 0; i < 8; ++i) {
    const int j0 = (i * 4 + wave) * 64;
#pragma unroll
    for (int nt = 0; nt < 4; ++nt) {
      const ushort* kr = kb + (size_t)(j0 + nt * 16 + m16) * 64 + quad * 8;
      bf16x8 kf0 = *reinterpret_cast<const bf16x8*>(kr);
      bf16x8 kf1 = *reinterpret_cast<const bf16x8*>(kr + 32);
      bf16x4 vf[4];
#pragma unroll
      for (int dt = 0; dt < 4; ++dt)
        vf[dt] = *reinterpret_cast<const bf16x4*>(
            vb + (size_t)(dt * 16 + m16) * 2048 + j0 + quad * 16 + nt * 4);
#pragma unroll
      for (int qs = 0; qs < 2; ++qs) {
        f32x4 st = (f32x4){0.f, 0.f, 0.f, 0.f};
        st = mfma32(kf0, qf[qs][0], st);
        st = mfma32(kf1, qf[qs][1], st);
        unsigned b0 = __float_as_uint(fexp2(st[0]));
        unsigned b1 = __float_as_uint(fexp2(st[1]));
        unsigned b2 = __float_as_uint(fexp2(st[2]));
        unsigned b3 = __float_as_uint(fexp2(st[3]));
        union { unsigned u[2]; bf16x4 s; } pk;
        pk.u[0] = __builtin_amdgcn_perm(b1, b0, 0x07060302u);
        pk.u[1] = __builtin_amdgcn_perm(b3, b2, 0x07060302u);
        rsacc[qs] = mfma16(ones, pk.s, rsacc[qs]);
#pragma unroll
        for (int dt = 0; dt < 4; ++dt)
          oacc[qs][dt] = mfma16(vf[dt], pk.s, oacc[qs][dt]);
      }
    }
  }

  // cross-wave combine
  if (wave > 0) {
#pragma unroll
    for (int qs = 0; qs < 2; ++qs)
#pragma unroll
      for (int dt = 0; dt < 4; ++dt)
        lo[wave - 1][qs * 4 + dt][lane] = oacc[qs][dt];
  }
  if (quad == 0) {
    lrs[wave][0][m16] = rsacc[0][0];  // all regs/quads identical (ones-A)
    lrs[wave][1][m16] = rsacc[1][0];
  }
  __syncthreads();
  if (wave == 0) {
#pragma unroll
    for (int qs = 0; qs < 2; ++qs) {
      float inv = 1.0f / (lrs[0][qs][m16] + lrs[1][qs][m16] +
                          lrs[2][qs][m16] + lrs[3][qs][m16]);
      const int nrow = q0 + qs * 16 + m16;
      ushort* orow = ao + ((size_t)(b * 2048 + nrow)) * 320 + h * 64;
#pragma unroll
      for (int dt = 0; dt < 4; ++dt) {
        f32x4 a = oacc[qs][dt];
        a += lo[0][qs * 4 + dt][lane];
        a += lo[1][qs * 4 + dt][lane];
        a += lo[2][qs * 4 + dt][lane];
        unsigned r0 = f2bf(a[0] * inv), r1 = f2bf(a[1] * inv);
        unsigned r2 = f2bf(a[2] * inv), r3 = f2bf(a[3] * inv);
        uint2 w;
        w.x = r0 | (r1 << 16);
        w.y = r2 | (r3 << 16);
        *reinterpret_cast<uint2*>(orow + dt * 16 + quad * 4) = w;
      }
    }
  }
}

// ---------------------------------------------------------------------------
// Kernel 3: output projection, bf16 MFMA, LDS-free: ao @ Wo + bo -> fp32
// grid (128 mt, 5 ct); wave computes 16m x 64n, K=320.
// ---------------------------------------------------------------------------
__global__ __launch_bounds__(256, 6) void oproj_gemm(
    const ushort* __restrict__ ao, const ushort* __restrict__ wt,
    const float* __restrict__ bo, float* __restrict__ out)
{
  const int mt = blockIdx.x, ct = blockIdx.y;
  const int wave = threadIdx.x >> 6, lane = threadIdx.x & 63;
  const int m16 = lane & 15, quad = lane >> 4;
  const int m0 = mt * 64 + wave * 16;
  const int n0 = ct * 64;
  const ushort* WTo = wt + (size_t)3 * 102400 + (size_t)n0 * 320 + quad * 8;
  const ushort* arow = ao + (size_t)(m0 + m16) * 320 + quad * 8;

  f32x4 acc[4];
#pragma unroll
  for (int ns = 0; ns < 4; ++ns) acc[ns] = (f32x4){0.f, 0.f, 0.f, 0.f};

#pragma unroll
  for (int kc = 0; kc < 10; ++kc) {
    bf16x8 af = *reinterpret_cast<const bf16x8*>(arow + kc * 32);
#pragma unroll
    for (int ns = 0; ns < 4; ++ns) {
      bf16x8 bf = *reinterpret_cast<const bf16x8*>(
          WTo + (size_t)(ns * 16 + m16) * 320 + kc * 32);
      acc[ns] = mfma32(af, bf, acc[ns]);
    }
  }

  float bb[4];
#pragma unroll
  for (int ns = 0; ns < 4; ++ns) bb[ns] = bo[n0 + ns * 16 + m16];
  const int mrow = m0 + quad * 4;
#pragma unroll
  for (int ns = 0; ns < 4; ++ns)
#pragma unroll
    for (int r = 0; r < 4; ++r)
      out[(size_t)(mrow + r) * 320 + n0 + ns * 16 + m16] = acc[ns][r] + bb[ns];
}

// ---------------------------------------------------------------------------
extern "C" void kernel_launch(void* const* d_in, const int* in_sizes, int n_in,
                              void* d_out, int out_size, void* d_ws, size_t ws_size,
                              hipStream_t stream) {
  const float* x    = (const float*)d_in[0];
  const float* edge = (const float*)d_in[1];
  const float* Wq   = (const float*)d_in[2];
  const float* Wk   = (const float*)d_in[3];
  const float* Wv   = (const float*)d_in[4];
  const float* Wo   = (const float*)d_in[5];
  const float* bo   = (const float*)d_in[6];
  float* out = (float*)d_out;

  // workspace (bf16 ushorts): xb 8192x320; wt 4x320x320; qp/kp/vS 20x2048x64;
  // ao 8192x320  => ~27 MB
  ushort* xb = (ushort*)d_ws;
  ushort* wt = xb + (size_t)8192 * 320;
  ushort* qp = wt + (size_t)4 * 320 * 320;
  ushort* kp = qp + (size_t)20 * 2048 * 64;
  ushort* vS = kp + (size_t)20 * 2048 * 64;
  ushort* ao = vS + (size_t)20 * 2048 * 64;

  xcvt_kernel<<<2560, 256, 0, stream>>>(x, xb);
  wtrans_kernel<<<dim3(10, 10, 4), dim3(32, 8), 0, stream>>>(Wq, Wk, Wv, Wo, wt);
  qkv_gemm<<<dim3(128, 5, 3), 256, 0, stream>>>(xb, edge, wt, qp, kp, vS);
  attn_kernel<<<dim3(64, 20), 256, 0, stream>>>(qp, kp, vS, ao);
  oproj_gemm<<<dim3(128, 5), 256, 0, stream>>>(ao, wt, bo, out);
}

// Round 4
// 142.206 us; speedup vs baseline: 2.4859x; 1.6226x over previous
//
#include <hip/hip_runtime.h>
#include <hip/hip_bf16.h>
#include <math.h>

// B=4, N=2048, C=320, H=5, D=64, INNER=320, BH=20
// logit = (q*0.125*log2e*e_i) . (k*e_j); softmax via exp2 (bounded, no max).
// e_bh = edge[(b+h)%4]  (batch-minor edge tiling vs batch-major heads)
//
// All intermediates are stored fragment-major so every main-loop load is a
// lane-contiguous b128 (addr = tile_base + lane*16B):
//  xb  tiles (mt2=m/16, kc=k/32): elem (qq*16+mm)*8+e  = x[m][k], qq=(k%32)>>3
//  wt  tiles (z, nt2=n/16, kc):   elem (qq*16+nn)*8+e  = W[k][n]
//  kS  [bh][j/16][d/32][slot]:    slot ((d>>3)&3)*16+(j&15), e=d&7
//  vS  [bh][d/16][j/64][kb][slot]: kb=(j>>5)&1, j32=j&31, qq=(j32>>2)&3,
//       e=(j32>>4)*4+(j32&3), slot (qq*16+(d&15))*8+e   (PV mfma32 A-frag)
//  ao  tiles like xb (A-operand of oproj)
//  qp  row-major [bh][n][64]  (loaded once per attn block)

typedef short bf16x8 __attribute__((ext_vector_type(8)));
typedef float f32x4 __attribute__((ext_vector_type(4)));

static __device__ __forceinline__ ushort f2bf(float f) {
  union { float f; unsigned u; } v; v.f = f;
  unsigned r = (v.u + 0x7fffu + ((v.u >> 16) & 1u)) >> 16;
  return (ushort)r;
}
static __device__ __forceinline__ float fexp2(float x) {
#if __has_builtin(__builtin_amdgcn_exp2f)
  return __builtin_amdgcn_exp2f(x);
#else
  return exp2f(x);
#endif
}
static __device__ __forceinline__ f32x4 mfma32(bf16x8 a, bf16x8 b, f32x4 c) {
  return __builtin_amdgcn_mfma_f32_16x16x32_bf16(a, b, c, 0, 0, 0);
}

// ---------------------------------------------------------------------------
// Prep 1: x fp32 -> bf16, fragment-major tiles. grid (512 mt2, 5), 256 thr.
// ---------------------------------------------------------------------------
__global__ __launch_bounds__(256) void xcvt_kernel(
    const float* __restrict__ x, ushort* __restrict__ xb)
{
  const int t = threadIdx.x;
  const int mt2 = blockIdx.x;
  const int kc = blockIdx.y * 2 + (t >> 7);
  const int f = (t & 127) * 4;            // elem index in tile
  const int qq = f >> 7, mm = (f >> 3) & 15, e0 = f & 7;
  float4 v = *reinterpret_cast<const float4*>(
      x + (size_t)(mt2 * 16 + mm) * 320 + kc * 32 + qq * 8 + e0);
  ushort4 o = { f2bf(v.x), f2bf(v.y), f2bf(v.z), f2bf(v.w) };
  *reinterpret_cast<ushort4*>(xb + (size_t)(mt2 * 10 + kc) * 512 + f) = o;
}

// ---------------------------------------------------------------------------
// Prep 2: W fp32 [k][n] -> bf16 fragment-major tiles. grid (20 nt2,10 kc,4 z)
// ---------------------------------------------------------------------------
__global__ __launch_bounds__(256) void wtrans_kernel(
    const float* __restrict__ Wq, const float* __restrict__ Wk,
    const float* __restrict__ Wv, const float* __restrict__ Wo,
    ushort* __restrict__ wt)
{
  const int z = blockIdx.z;
  const float* W = z == 0 ? Wq : z == 1 ? Wk : z == 2 ? Wv : Wo;
  const int nt2 = blockIdx.x, kc = blockIdx.y;
  const int f = threadIdx.x * 2;
  const int qq = f >> 7, nn = (f >> 3) & 15, e0 = f & 7;
  const int k = kc * 32 + qq * 8 + e0, n = nt2 * 16 + nn;
  float v0 = W[(size_t)k * 320 + n];
  float v1 = W[(size_t)(k + 1) * 320 + n];
  ushort2 o = { f2bf(v0), f2bf(v1) };
  *reinterpret_cast<ushort2*>(
      wt + (size_t)z * 102400 + (size_t)(nt2 * 10 + kc) * 512 + f) = o;
}

// ---------------------------------------------------------------------------
// Kernel 1: QKV projection, bf16 MFMA, LDS-free, fully-coalesced frag loads.
// grid (128 mt, 5 h, 3 z); wave computes 16m x 64n, K=320.
// ---------------------------------------------------------------------------
__global__ __launch_bounds__(256, 4) void qkv_gemm(
    const ushort* __restrict__ xb, const float* __restrict__ edge,
    const ushort* __restrict__ wt,
    ushort* __restrict__ qp, ushort* __restrict__ kS, ushort* __restrict__ vS)
{
  const int mt = blockIdx.x, h = blockIdx.y, z = blockIdx.z;
  const int wave = threadIdx.x >> 6, lane = threadIdx.x & 63;
  const int m16 = lane & 15, quad = lane >> 4;
  const int m0 = mt * 64 + wave * 16;
  const ushort* atile = xb + (size_t)(mt * 4 + wave) * 10 * 512 + lane * 8;
  const ushort* btile = wt + (size_t)z * 102400 + (size_t)(h * 4) * 10 * 512 + lane * 8;

  f32x4 acc[4];
#pragma unroll
  for (int ns = 0; ns < 4; ++ns) acc[ns] = (f32x4){0.f, 0.f, 0.f, 0.f};

#pragma unroll
  for (int kc = 0; kc < 10; ++kc) {
    bf16x8 af = *reinterpret_cast<const bf16x8*>(atile + kc * 512);
#pragma unroll
    for (int ns = 0; ns < 4; ++ns) {
      bf16x8 bf = *reinterpret_cast<const bf16x8*>(btile + (ns * 10 + kc) * 512);
      acc[ns] = mfma32(af, bf, acc[ns]);
    }
  }

  // C/D: lane holds m = m0 + quad*4 + r, col d = ns*16 + m16
  const float QSCALE = 0.18033688011112042f;  // 0.125 * log2(e)
  const int mrow = m0 + quad * 4;
  const int b = mrow >> 11;
  const int n = mrow & 2047;
  const int bh = b * 5 + h;
  if (z == 2) {
    // vS[bh][dt][jb][kb][(qq*16+d16)*8 + e]; here qq=quad, e=(wave&1)*4+r
#pragma unroll
    for (int ns = 0; ns < 4; ++ns) {
      ushort4 o = { f2bf(acc[ns][0]), f2bf(acc[ns][1]),
                    f2bf(acc[ns][2]), f2bf(acc[ns][3]) };
      size_t addr = (size_t)bh * 131072 + (size_t)ns * 32768 +
                    (size_t)(mt & 31) * 1024 + (wave >> 1) * 512 +
                    (quad * 16 + m16) * 8 + (wave & 1) * 4;
      *reinterpret_cast<ushort4*>(vS + addr) = o;
    }
  } else if (z == 1) {
    const float* eb = edge + (size_t)((b + h) & 3) * 2048;
    // kS[bh][j>>4][d>>5][(((d>>3)&3)*16 + (j&15))*8 + (d&7)]
    const size_t base = (size_t)bh * 131072 + (size_t)((mt & 31) * 4 + wave) * 1024;
#pragma unroll
    for (int ns = 0; ns < 4; ++ns) {
      int d = ns * 16 + m16;
      size_t a0 = base + (ns >> 1) * 512 +
                  (((ns & 1) * 2 + (m16 >> 3)) * 16 + quad * 4) * 8 + (m16 & 7);
#pragma unroll
      for (int r = 0; r < 4; ++r)
        kS[a0 + (size_t)r * 8] = f2bf(acc[ns][r] * eb[n + r]);
    }
  } else {
    const float* eb = edge + (size_t)((b + h) & 3) * 2048;
    float e[4];
#pragma unroll
    for (int r = 0; r < 4; ++r) e[r] = eb[n + r] * QSCALE;
    ushort* dst = qp + ((size_t)bh * 2048 + n) * 64;
#pragma unroll
    for (int ns = 0; ns < 4; ++ns) {
      int d = ns * 16 + m16;
#pragma unroll
      for (int r = 0; r < 4; ++r)
        dst[(size_t)r * 64 + d] = f2bf(acc[ns][r] * e[r]);
    }
  }
}

// ---------------------------------------------------------------------------
// Kernel 2: attention. grid (64 qt, 20 bh); 4 waves j-split over same 32 q.
//   S^T = K Q^T (mfma32); P^T = exp2 -> bf16 packed in-register;
//   rowsum & PV via mfma32 (V swizzle absorbs the k-permutation).
//   All K/V loads lane-contiguous b128.
// ---------------------------------------------------------------------------
__global__ __launch_bounds__(256, 4) void attn_kernel(
    const ushort* __restrict__ qp, const ushort* __restrict__ kS,
    const ushort* __restrict__ vS, ushort* __restrict__ ao)
{
  __shared__ f32x4 lo[3][8][64];   // 24 KB cross-wave partials
  __shared__ float lrs[4][2][16];
  const int qt = blockIdx.x, bh = blockIdx.y;
  const int b = bh / 5, h = bh % 5;
  const int wave = threadIdx.x >> 6, lane = threadIdx.x & 63;
  const int m16 = lane & 15, quad = lane >> 4;
  const int q0 = qt * 32;

  bf16x8 qf[2][2];
#pragma unroll
  for (int qs = 0; qs < 2; ++qs) {
    const ushort* qrow = qp + ((size_t)bh * 2048 + q0 + qs * 16 + m16) * 64;
    qf[qs][0] = *reinterpret_cast<const bf16x8*>(qrow + quad * 8);
    qf[qs][1] = *reinterpret_cast<const bf16x8*>(qrow + 32 + quad * 8);
  }
  const ushort* kb_p = kS + (size_t)bh * 131072 + lane * 8;
  const ushort* vb_p = vS + (size_t)bh * 131072 + lane * 8;

  f32x4 oacc[2][4], rsacc[2];
#pragma unroll
  for (int qs = 0; qs < 2; ++qs) {
    rsacc[qs] = (f32x4){0.f, 0.f, 0.f, 0.f};
    for (int dt = 0; dt < 4; ++dt) oacc[qs][dt] = (f32x4){0.f, 0.f, 0.f, 0.f};
  }
  const bf16x8 ones8 = {(short)16256, (short)16256, (short)16256, (short)16256,
                        (short)16256, (short)16256, (short)16256, (short)16256};

  for (int i = 0; i < 8; ++i) {
    const int jb = i * 4 + wave;          // 64-j block index
#pragma unroll
    for (int kb = 0; kb < 2; ++kb) {      // 32-j halves
      bf16x8 kf[2][2];
#pragma unroll
      for (int s = 0; s < 2; ++s)
#pragma unroll
        for (int hf = 0; hf < 2; ++hf)
          kf[s][hf] = *reinterpret_cast<const bf16x8*>(
              kb_p + (size_t)(jb * 4 + kb * 2 + s) * 1024 + hf * 512);
      bf16x8 vf[4];
#pragma unroll
      for (int dt = 0; dt < 4; ++dt)
        vf[dt] = *reinterpret_cast<const bf16x8*>(
            vb_p + (size_t)dt * 32768 + (size_t)jb * 1024 + kb * 512);
#pragma unroll
      for (int qs = 0; qs < 2; ++qs) {
        f32x4 st0 = (f32x4){0.f, 0.f, 0.f, 0.f};
        f32x4 st1 = (f32x4){0.f, 0.f, 0.f, 0.f};
        st0 = mfma32(kf[0][0], qf[qs][0], st0);
        st0 = mfma32(kf[0][1], qf[qs][1], st0);
        st1 = mfma32(kf[1][0], qf[qs][0], st1);
        st1 = mfma32(kf[1][1], qf[qs][1], st1);
        unsigned b0 = __float_as_uint(fexp2(st0[0]));
        unsigned b1 = __float_as_uint(fexp2(st0[1]));
        unsigned b2 = __float_as_uint(fexp2(st0[2]));
        unsigned b3 = __float_as_uint(fexp2(st0[3]));
        unsigned b4 = __float_as_uint(fexp2(st1[0]));
        unsigned b5 = __float_as_uint(fexp2(st1[1]));
        unsigned b6 = __float_as_uint(fexp2(st1[2]));
        unsigned b7 = __float_as_uint(fexp2(st1[3]));
        union { unsigned u[4]; bf16x8 v; } pk;
        pk.u[0] = __builtin_amdgcn_perm(b1, b0, 0x07060302u);
        pk.u[1] = __builtin_amdgcn_perm(b3, b2, 0x07060302u);
        pk.u[2] = __builtin_amdgcn_perm(b5, b4, 0x07060302u);
        pk.u[3] = __builtin_amdgcn_perm(b7, b6, 0x07060302u);
        rsacc[qs] = mfma32(ones8, pk.v, rsacc[qs]);
#pragma unroll
        for (int dt = 0; dt < 4; ++dt)
          oacc[qs][dt] = mfma32(vf[dt], pk.v, oacc[qs][dt]);
      }
    }
  }

  // cross-wave combine
  if (wave > 0) {
#pragma unroll
    for (int qs = 0; qs < 2; ++qs)
#pragma unroll
      for (int dt = 0; dt < 4; ++dt)
        lo[wave - 1][qs * 4 + dt][lane] = oacc[qs][dt];
  }
  if (quad == 0) {
    lrs[wave][0][m16] = rsacc[0][0];  // all regs identical (ones-A)
    lrs[wave][1][m16] = rsacc[1][0];
  }
  __syncthreads();
  if (wave == 0) {
#pragma unroll
    for (int qs = 0; qs < 2; ++qs) {
      float inv = 1.0f / (lrs[0][qs][m16] + lrs[1][qs][m16] +
                          lrs[2][qs][m16] + lrs[3][qs][m16]);
      const int mt2 = b * 128 + qt * 2 + qs;  // ao tile row
#pragma unroll
      for (int dt = 0; dt < 4; ++dt) {
        f32x4 a = oacc[qs][dt];
        a += lo[0][qs * 4 + dt][lane];
        a += lo[1][qs * 4 + dt][lane];
        a += lo[2][qs * 4 + dt][lane];
        unsigned r0 = f2bf(a[0] * inv), r1 = f2bf(a[1] * inv);
        unsigned r2 = f2bf(a[2] * inv), r3 = f2bf(a[3] * inv);
        uint2 w;
        w.x = r0 | (r1 << 16);
        w.y = r2 | (r3 << 16);
        // ao tile write: kc = h*2 + (dt>>1); qq=(dt&1)*2+(quad>>1); e0=(quad&1)*4
        size_t addr = (size_t)(mt2 * 10 + h * 2 + (dt >> 1)) * 512 +
                      ((((dt & 1) * 2 + (quad >> 1)) * 16 + m16)) * 8 +
                      (quad & 1) * 4;
        *reinterpret_cast<uint2*>(ao + addr) = w;
      }
    }
  }
}

// ---------------------------------------------------------------------------
// Kernel 3: output projection: ao(tiled bf16) @ Wo + bo -> fp32.
// grid (128 mt, 5 ct); wave computes 16m x 64n, K=320. Coalesced frag loads.
// ---------------------------------------------------------------------------
__global__ __launch_bounds__(256, 4) void oproj_gemm(
    const ushort* __restrict__ ao, const ushort* __restrict__ wt,
    const float* __restrict__ bo, float* __restrict__ out)
{
  const int mt = blockIdx.x, ct = blockIdx.y;
  const int wave = threadIdx.x >> 6, lane = threadIdx.x & 63;
  const int m16 = lane & 15, quad = lane >> 4;
  const int m0 = mt * 64 + wave * 16;
  const int n0 = ct * 64;
  const ushort* atile = ao + (size_t)(mt * 4 + wave) * 10 * 512 + lane * 8;
  const ushort* btile = wt + (size_t)3 * 102400 + (size_t)(ct * 4) * 10 * 512 + lane * 8;

  f32x4 acc[4];
#pragma unroll
  for (int ns = 0; ns < 4; ++ns) acc[ns] = (f32x4){0.f, 0.f, 0.f, 0.f};

#pragma unroll
  for (int kc = 0; kc < 10; ++kc) {
    bf16x8 af = *reinterpret_cast<const bf16x8*>(atile + kc * 512);
#pragma unroll
    for (int ns = 0; ns < 4; ++ns) {
      bf16x8 bf = *reinterpret_cast<const bf16x8*>(btile + (ns * 10 + kc) * 512);
      acc[ns] = mfma32(af, bf, acc[ns]);
    }
  }

  float bb[4];
#pragma unroll
  for (int ns = 0; ns < 4; ++ns) bb[ns] = bo[n0 + ns * 16 + m16];
  const int mrow = m0 + quad * 4;
#pragma unroll
  for (int ns = 0; ns < 4; ++ns)
#pragma unroll
    for (int r = 0; r < 4; ++r)
      out[(size_t)(mrow + r) * 320 + n0 + ns * 16 + m16] = acc[ns][r] + bb[ns];
}

// ---------------------------------------------------------------------------
extern "C" void kernel_launch(void* const* d_in, const int* in_sizes, int n_in,
                              void* d_out, int out_size, void* d_ws, size_t ws_size,
                              hipStream_t stream) {
  const float* x    = (const float*)d_in[0];
  const float* edge = (const float*)d_in[1];
  const float* Wq   = (const float*)d_in[2];
  const float* Wk   = (const float*)d_in[3];
  const float* Wv   = (const float*)d_in[4];
  const float* Wo   = (const float*)d_in[5];
  const float* bo   = (const float*)d_in[6];
  float* out = (float*)d_out;

  ushort* xb = (ushort*)d_ws;                       // 8192*320
  ushort* wt = xb + (size_t)8192 * 320;             // 4*320*320
  ushort* qp = wt + (size_t)4 * 320 * 320;          // 20*2048*64
  ushort* kS = qp + (size_t)20 * 2048 * 64;
  ushort* vS = kS + (size_t)20 * 2048 * 64;
  ushort* ao = vS + (size_t)20 * 2048 * 64;

  xcvt_kernel<<<dim3(512, 5), 256, 0, stream>>>(x, xb);
  wtrans_kernel<<<dim3(20, 10, 4), 256, 0, stream>>>(Wq, Wk, Wv, Wo, wt);
  qkv_gemm<<<dim3(128, 5, 3), 256, 0, stream>>>(xb, edge, wt, qp, kS, vS);
  attn_kernel<<<dim3(64, 20), 256, 0, stream>>>(qp, kS, vS, ao);
  oproj_gemm<<<dim3(128, 5), 256, 0, stream>>>(ao, wt, bo, out);
}